// Round 2
// 247.383 us; speedup vs baseline: 1.0283x; 1.0283x over previous
//
#include <hip/hip_runtime.h>
#include <cstdint>
#include <cstddef>

typedef __bf16 bf16;
typedef __bf16 bf16x4 __attribute__((ext_vector_type(4)));
typedef __bf16 bf16x8 __attribute__((ext_vector_type(8)));
typedef float  f32x4  __attribute__((ext_vector_type(4)));
typedef float  f32x16 __attribute__((ext_vector_type(16)));

#define BATCH 4
#define SEQ   2048
#define DIM   1024
#define LDP   2112   // padded leading dim for P and Vt

// RNE float -> bf16
__device__ __forceinline__ bf16 to_bf16(float f) {
    unsigned u = __builtin_bit_cast(unsigned, f);
    u += 0x7fffu + ((u >> 16) & 1u);
    unsigned short h = (unsigned short)(u >> 16);
    return __builtin_bit_cast(bf16, h);
}

// async global->LDS, 16B per lane. LDS base must be wave-uniform; HW adds lane*16.
__device__ __forceinline__ void load16_lds(const bf16* g, bf16* l) {
    __builtin_amdgcn_global_load_lds(
        (__attribute__((address_space(1))) void*)(g),
        (__attribute__((address_space(3))) void*)(l),
        16, 0, 0);
}

#define BARRIER() do { asm volatile("" ::: "memory"); \
                       __builtin_amdgcn_s_barrier();  \
                       asm volatile("" ::: "memory"); } while (0)
#define LGKM0()   do { asm volatile("s_waitcnt lgkmcnt(0)" ::: "memory"); \
                       __builtin_amdgcn_sched_barrier(0); } while (0)
#define VM4()     asm volatile("s_waitcnt vmcnt(4)" ::: "memory")
#define VM0()     asm volatile("s_waitcnt vmcnt(0)" ::: "memory")

// ---------------------------------------------------------------------------
// 8-phase 256x256 core (BK=64), 512 threads = 8 waves (2M x 4N), per-wave
// 128x64 output, 16x16x32 MFMA. LDS: As/Bs each [2 dbuf][256 rows][64 k] bf16
// = 64 KB each, 128 KB total -> 1 block/CU, 2 waves/SIMD.
// Chunk swizzle: physical 16B-chunk p = logical c ^ (row&7); staged via
// pre-swizzled GLOBAL source (linear LDS dest for global_load_lds).
// Schedule (race-free by construction): during tile t,
//   P0: read a[m0-3],b[n0-1]; stage B1(t+1) -> other buffer (safe)
//   P1: read b[n2-3];          stage A1(t+1) -> other buffer (safe)
//   P2: read a[m4-7];          stage B0(t+2) -> CURRENT buf, B last read P1
//   P3: (no reads);            stage A0(t+2) -> CURRENT buf, A last read P2
// Boundary: vmcnt(4) once per tile (2 half-tiles = 4 loads stay in flight),
// never vmcnt(0) except at the t+2>=NT tail.
// ---------------------------------------------------------------------------

// stage one half-tile: 128 rows x 64 k of one matrix (2 gload_lds / thread).
__device__ __forceinline__ void stage_half(
    const bf16* __restrict__ srcRow0, int ld, int k0, bf16* dstHalfBase)
{
    const int tid  = threadIdx.x;
    const int wave = tid >> 6;
    const int lane = tid & 63;
    const int rg   = lane >> 3;                 // row within 8-row group
    const int scoff = ((lane & 7) ^ rg) * 8;    // pre-swizzled global chunk
#pragma unroll
    for (int j = 0; j < 2; ++j) {
        const int r = wave * 16 + j * 8;        // wave-uniform LDS row base
        load16_lds(srcRow0 + (size_t)(r + rg) * ld + k0 + scoff,
                   dstHalfBase + r * 64);
    }
}

template<int MB, int NB>
__device__ __forceinline__ void mfma_quad(
    const bf16x8 a[4][2], const bf16x8 b[4][2], f32x4 acc[8][4])
{
    __builtin_amdgcn_s_setprio(1);
#pragma unroll
    for (int m = 0; m < 4; ++m)
#pragma unroll
        for (int n = 0; n < 2; ++n)
#pragma unroll
            for (int ks = 0; ks < 2; ++ks)
                acc[MB + m][NB + n] = __builtin_amdgcn_mfma_f32_16x16x32_bf16(
                    a[m][ks], b[NB + n][ks], acc[MB + m][NB + n], 0, 0, 0);
    __builtin_amdgcn_s_setprio(0);
}

__device__ __forceinline__ void gemm8_core(
    const bf16* __restrict__ Ablk, const bf16* __restrict__ Bblk,
    int K, int lda, int ldb, bf16* As, bf16* Bs, f32x4 acc[8][4])
{
    const int tid  = threadIdx.x;
    const int lane = tid & 63;
    const int wave = tid >> 6;
    const int wr   = wave >> 2;          // 0..1 (M)
    const int wc   = wave & 3;           // 0..3 (N)
    const int r16  = lane & 15;
    const int g    = lane >> 4;
    const int r7   = r16 & 7;
    const int pk0  = ((g) ^ r7) * 8;         // phys chunk offset, ks=0
    const int pk1  = ((4 + g) ^ r7) * 8;     // ks=1
    const int arow = (wr * 128 + r16) * 64;
    const int brow = (wc * 64 + r16) * 64;
    const int NT   = K >> 6;

    // prologue: tile0 {B0,A0,B1,A1} + tile1 {B0,A0}  (order matters for vmcnt)
    stage_half(Bblk, ldb, 0, Bs);
    stage_half(Ablk, lda, 0, As);
    stage_half(Bblk + (size_t)128 * ldb, ldb, 0, Bs + 8192);
    stage_half(Ablk + (size_t)128 * lda, lda, 0, As + 8192);
    stage_half(Bblk, ldb, 64, Bs + 16384);
    stage_half(Ablk, lda, 64, As + 16384);
    VM4();                                // tile0 resident; tile1 B0/A0 in flight
    BARRIER();

    bf16x8 a[4][2], b[4][2];
#pragma unroll 2
    for (int t = 0; t < NT; ++t) {
        bf16* Ac = As + (t & 1) * 16384;
        bf16* Bc = Bs + (t & 1) * 16384;
        bf16* An = As + ((t + 1) & 1) * 16384;
        bf16* Bn = Bs + ((t + 1) & 1) * 16384;
        const int k1 = (t + 1) << 6;
        const int k2 = (t + 2) << 6;

        // ---- P0: a[m0-3], b[n0-1]; stage B1(t+1)
#pragma unroll
        for (int m = 0; m < 4; ++m) {
            a[m][0] = *(const bf16x8*)(Ac + arow + m * 1024 + pk0);
            a[m][1] = *(const bf16x8*)(Ac + arow + m * 1024 + pk1);
        }
#pragma unroll
        for (int n = 0; n < 2; ++n) {
            b[n][0] = *(const bf16x8*)(Bc + brow + n * 1024 + pk0);
            b[n][1] = *(const bf16x8*)(Bc + brow + n * 1024 + pk1);
        }
        if (t + 1 < NT) stage_half(Bblk + (size_t)128 * ldb, ldb, k1, Bn + 8192);
        BARRIER(); LGKM0();
        mfma_quad<0, 0>(a, b, acc);
        BARRIER();

        // ---- P1: b[n2-3]; stage A1(t+1)
#pragma unroll
        for (int n = 2; n < 4; ++n) {
            b[n][0] = *(const bf16x8*)(Bc + brow + n * 1024 + pk0);
            b[n][1] = *(const bf16x8*)(Bc + brow + n * 1024 + pk1);
        }
        if (t + 1 < NT) stage_half(Ablk + (size_t)128 * lda, lda, k1, An + 8192);
        BARRIER(); LGKM0();
        mfma_quad<0, 2>(a, b, acc);
        BARRIER();

        // ---- P2: a[m4-7]; stage B0(t+2) into current buffer (B free since P1)
#pragma unroll
        for (int m = 0; m < 4; ++m) {
            a[m][0] = *(const bf16x8*)(Ac + arow + 4096 + m * 1024 + pk0);
            a[m][1] = *(const bf16x8*)(Ac + arow + 4096 + m * 1024 + pk1);
        }
        if (t + 2 < NT) stage_half(Bblk, ldb, k2, Bc);
        BARRIER(); LGKM0();
        mfma_quad<4, 2>(a, b, acc);
        BARRIER();

        // ---- P3: stage A0(t+2) into current buffer (A free since P2)
        if (t + 2 < NT) stage_half(Ablk, lda, k2, Ac);
        BARRIER(); LGKM0();
        mfma_quad<4, 0>(a, b, acc);
        if (t + 1 < NT) {
            if (t + 2 < NT) { VM4(); } else { VM0(); }
        }
        BARRIER();
    }
}

// ---------------------------------------------------------------------------
// Legacy 32x32x16 128-tile core (still used by gemm_pv this round)
// ---------------------------------------------------------------------------
__device__ __forceinline__ void stage_tiles(
    const bf16* __restrict__ Abase, const bf16* __restrict__ Bbase,
    int k0, int lda, int ldb, bf16* As, bf16* Bs)
{
    const int tid   = threadIdx.x;
    const int wave  = tid >> 6;
    const int lane  = tid & 63;
    const int srow0 = wave * 8 + (lane >> 3);
    const int scoff = (((lane & 7) ^ ((lane >> 3) & 7)) * 8);
    const int ldsW  = wave * 512;
#pragma unroll
    for (int j = 0; j < 4; ++j) {
        load16_lds(Abase + (size_t)(j * 32 + srow0) * lda + k0 + scoff,
                   As + j * 2048 + ldsW);
        load16_lds(Bbase + (size_t)(j * 32 + srow0) * ldb + k0 + scoff,
                   Bs + j * 2048 + ldsW);
    }
}

__device__ __forceinline__ void gemm_core64_32(
    const bf16* __restrict__ Abase, const bf16* __restrict__ Bbase,
    int K, int lda, int ldb, bf16* As, bf16* Bs, f32x16 acc[2][2])
{
    const int tid  = threadIdx.x;
    const int lane = tid & 63;
    const int wave = tid >> 6;
    const int wm   = (wave >> 1) * 64;
    const int wn   = (wave & 1) * 64;
    const int r32  = lane & 31;
    const int hi   = lane >> 5;

    for (int k0 = 0; k0 < K; k0 += 64) {
        __syncthreads();
        stage_tiles(Abase, Bbase, k0, lda, ldb, As, Bs);
        __syncthreads();
#pragma unroll
        for (int t = 0; t < 4; ++t) {
            bf16x8 af[2], bfr[2];
            const int p = (2 * t + hi) ^ (r32 & 7);
#pragma unroll
            for (int i = 0; i < 2; ++i) {
                af[i]  = *(const bf16x8*)(As + (wm + i * 32 + r32) * 64 + p * 8);
                bfr[i] = *(const bf16x8*)(Bs + (wn + i * 32 + r32) * 64 + p * 8);
            }
#pragma unroll
            for (int mi = 0; mi < 2; ++mi)
#pragma unroll
                for (int ni = 0; ni < 2; ++ni)
                    acc[mi][ni] = __builtin_amdgcn_mfma_f32_32x32x16_bf16(
                        af[mi], bfr[ni], acc[mi][ni], 0, 0, 0);
        }
    }
}

__device__ __forceinline__ int c32_row(int reg, int hi) {
    return (reg & 3) + 8 * (reg >> 2) + 4 * hi;
}

// ---------------------------------------------------------------------------
// Merged projection (8-phase 256^2): blocks [0,256) -> Q,K = X @ W{q,k}T^T;
// blocks [256,384) -> Vt[b] = WvT @ X[b]^T.
// ---------------------------------------------------------------------------
__global__ __launch_bounds__(512, 2) void proj_gemm8(
    const bf16* __restrict__ xb, const bf16* __restrict__ Wt,
    bf16* __restrict__ Q, bf16* __restrict__ Kb, bf16* __restrict__ Vt)
{
    __shared__ bf16 As[32768];
    __shared__ bf16 Bs[32768];
    f32x4 acc[8][4] = {};

    const int r = blockIdx.x;
    const bf16 *Ab, *Bb;
    bf16* Cb;
    int ldc;
    if (r < 256) {                        // Q/K part
        const int my = r >> 3, j = r & 7;
        Ab = xb + (size_t)my * 256 * DIM;
        Bb = Wt + (size_t)((j >> 2) ? DIM * DIM : 0) + (size_t)(j & 3) * 256 * DIM;
        bf16* dst = (j >> 2) ? Kb : Q;
        Cb = dst + (size_t)my * 256 * DIM + (size_t)(j & 3) * 256;
        ldc = DIM;
    } else {                              // Vt part
        const int u = r - 256;
        const int bz = u >> 5, w = u & 31;
        const int vy = w >> 3, vx = w & 7;
        Ab = Wt + (size_t)2 * DIM * DIM + (size_t)vy * 256 * DIM;
        Bb = xb + (size_t)bz * SEQ * DIM + (size_t)vx * 256 * DIM;
        Cb = Vt + (size_t)bz * DIM * LDP + (size_t)vy * 256 * LDP + (size_t)vx * 256;
        ldc = LDP;
    }
    gemm8_core(Ab, Bb, DIM, DIM, DIM, As, Bs, acc);

    const int lane = threadIdx.x & 63;
    const int wave = threadIdx.x >> 6;
    const int wr = wave >> 2, wc = wave & 3;
    const int r16 = lane & 15, g = lane >> 4;
    const int row0 = wr * 128 + g * 4;
    const int col0 = wc * 64 + r16;
#pragma unroll
    for (int m = 0; m < 8; ++m)
#pragma unroll
        for (int n = 0; n < 4; ++n)
#pragma unroll
            for (int rr = 0; rr < 4; ++rr)
                Cb[(size_t)(row0 + m * 16 + rr) * ldc + col0 + n * 16] =
                    to_bf16(acc[m][n][rr]);
}

// ---------------------------------------------------------------------------
// scores (8-phase 256^2): P' = exp((Q @ K^T)/32) (bf16, ldc=LDP), fp32 row
// sums via atomics. grid = 256 blocks (bz*64 + by*8 + bx) -> exactly 1/CU.
// ---------------------------------------------------------------------------
__global__ __launch_bounds__(512, 2) void gemm_scores8(
    const bf16* __restrict__ Qm, const bf16* __restrict__ Kb,
    bf16* __restrict__ P, float* __restrict__ lsum)
{
    __shared__ bf16 As[32768];
    __shared__ bf16 Bs[32768];
    f32x4 acc[8][4] = {};

    const int d = blockIdx.x;
    const int bx = d & 7, by = (d >> 3) & 7, bz = d >> 6;
    const bf16* Ab = Qm + (size_t)bz * SEQ * DIM + (size_t)by * 256 * DIM;
    const bf16* Bb = Kb + (size_t)bz * SEQ * DIM + (size_t)bx * 256 * DIM;
    gemm8_core(Ab, Bb, DIM, DIM, DIM, As, Bs, acc);

    bf16* Cb  = P + (size_t)bz * SEQ * LDP;
    float* ls = lsum + (size_t)bz * SEQ;
    const int lane = threadIdx.x & 63;
    const int wave = threadIdx.x >> 6;
    const int wr = wave >> 2, wc = wave & 3;
    const int r16 = lane & 15, g = lane >> 4;
    const int rowB = by * 256 + wr * 128 + g * 4;
    const int colB = bx * 256 + wc * 64 + r16;
#pragma unroll
    for (int m = 0; m < 8; ++m)
#pragma unroll
        for (int rr = 0; rr < 4; ++rr) {
            float s = 0.0f;
#pragma unroll
            for (int n = 0; n < 4; ++n) {
                const float e = __expf(acc[m][n][rr] * 0.03125f);
                s += e;
                Cb[(size_t)(rowB + m * 16 + rr) * LDP + colB + n * 16] = to_bf16(e);
            }
            s += __shfl_xor(s, 1);
            s += __shfl_xor(s, 2);
            s += __shfl_xor(s, 4);
            s += __shfl_xor(s, 8);
            if (r16 == 0)
                atomicAdd(ls + rowB + m * 16 + rr, s);
        }
}

// ---------------------------------------------------------------------------
// PV GEMM (legacy 32x32 core): out = (P' @ Vt^T) / l, fp32. grid = (8, 16, 4).
// ---------------------------------------------------------------------------
__global__ __launch_bounds__(256, 4) void gemm_pv(
    const bf16* __restrict__ P, const bf16* __restrict__ Vt, float* __restrict__ C,
    const float* __restrict__ lsum)
{
    __shared__ bf16 As[8192];
    __shared__ bf16 Bs[8192];
    f32x16 acc[2][2] = {};

    const int d = blockIdx.x + 8 * (blockIdx.y + 16 * blockIdx.z);
    const int c = d & 7, j = d >> 3;
    const int bx = j & 7;
    const int p = c + 8 * (j >> 3);
    const int by = p & 15, bz = p >> 4;

    const bf16* Ab = P  + (size_t)bz * SEQ * LDP + (size_t)by * 128 * LDP;
    const bf16* Bb = Vt + (size_t)bz * DIM * LDP + (size_t)bx * 128 * LDP;
    float* Cb = C + (size_t)bz * SEQ * DIM;
    gemm_core64_32(Ab, Bb, SEQ, LDP, LDP, As, Bs, acc);

    const int lane = threadIdx.x & 63;
    const int wave = threadIdx.x >> 6;
    const int hi = lane >> 5, r32 = lane & 31;
    const int wm = (wave >> 1) * 64, wn = (wave & 1) * 64;
    const int rowBase = by * 128 + wm;
    const int colBase = bx * 128 + wn + r32;
    const float* ls = lsum + (size_t)bz * SEQ;
#pragma unroll
    for (int mi = 0; mi < 2; ++mi)
#pragma unroll
        for (int reg = 0; reg < 16; ++reg) {
            const int row = rowBase + mi * 32 + c32_row(reg, hi);
            const float inv = __builtin_amdgcn_rcpf(ls[row]);
#pragma unroll
            for (int ni = 0; ni < 2; ++ni)
                Cb[(size_t)row * DIM + colBase + ni * 32] = acc[mi][ni][reg] * inv;
        }
}

// ---------------------------------------------------------------------------
// Fused prep: blocks [0,8192) cast x fp32->bf16; blocks [8192,11264) transpose
// + cast weights; block 11264 zeroes lsum. All branches block-uniform.
// ---------------------------------------------------------------------------
__global__ __launch_bounds__(256) void prep(
    const float* __restrict__ x,  const float* __restrict__ wq,
    const float* __restrict__ wk, const float* __restrict__ wv,
    bf16* __restrict__ xb, bf16* __restrict__ Wt, float* __restrict__ lsum)
{
    __shared__ float tile[32][33];
    const int b = blockIdx.x;
    const int tid = threadIdx.x;
    if (b < 8192) {
        const size_t i = ((size_t)b * 256 + tid) * 4;
        const float4 v = *(const float4*)(x + i);
        bf16x4 o = { to_bf16(v.x), to_bf16(v.y), to_bf16(v.z), to_bf16(v.w) };
        *(bf16x4*)(xb + i) = o;
    } else if (b < 8192 + 3072) {
        const int t   = b - 8192;
        const int sel = t >> 10;
        const int n0  = (t & 31) * 32;
        const int k0  = ((t >> 5) & 31) * 32;
        const float* w = (sel == 0) ? wq : (sel == 1) ? wk : wv;
        const int tx = tid & 31, ty = tid >> 5;
#pragma unroll
        for (int j = 0; j < 32; j += 8)
            tile[ty + j][tx] = w[(size_t)(k0 + ty + j) * 1024 + n0 + tx];
        __syncthreads();
        bf16* dst = Wt + (size_t)sel * 1024 * 1024;
#pragma unroll
        for (int j = 0; j < 32; j += 8)
            dst[(size_t)(n0 + ty + j) * 1024 + k0 + tx] = to_bf16(tile[tx][ty + j]);
    } else {
#pragma unroll
        for (int i = 0; i < 32; ++i)
            lsum[i * 256 + tid] = 0.0f;
    }
}

// ---------------------------------------------------------------------------
extern "C" void kernel_launch(void* const* d_in, const int* in_sizes, int n_in,
                              void* d_out, int out_size, void* d_ws, size_t ws_size,
                              hipStream_t stream)
{
    const float* x  = (const float*)d_in[0];
    const float* wq = (const float*)d_in[1];
    const float* wk = (const float*)d_in[2];
    const float* wv = (const float*)d_in[3];
    float* out = (float*)d_out;
    char* ws = (char*)d_ws;

    // workspace layout (bytes)
    bf16*  xb   = (bf16*)(ws);                   // 16 MB [8192,1024]
    bf16*  Wt   = (bf16*)(ws + (16u << 20));     //  6 MB [3072,1024] (WqT|WkT|WvT)
    bf16*  Q    = (bf16*)(ws + (22u << 20));     // 16 MB [8192,1024]
    bf16*  Kb   = (bf16*)(ws + (38u << 20));     // 16 MB [8192,1024]
    bf16*  Vt   = (bf16*)(ws + (54u << 20));     // 17 MB [4][1024][LDP]
    bf16*  P    = (bf16*)(ws + (72u << 20));     // 33 MB [4][2048][LDP]
    float* lsum = (float*)(ws + (108u << 20));   // 32 KB [8192]

    prep<<<dim3(8192 + 3072 + 1), dim3(256), 0, stream>>>(
        x, wq, wk, wv, xb, Wt, lsum);

    // Q, K, Vt in one dispatch (8-phase 256^2 core)
    proj_gemm8<<<dim3(384), dim3(512), 0, stream>>>(xb, Wt, Q, Kb, Vt);

    // P' = exp(Q @ K^T / 32), row sums -> lsum (8-phase 256^2 core)
    gemm_scores8<<<dim3(256), dim3(512), 0, stream>>>(Q, Kb, P, lsum);

    // out = (P' @ Vt^T) / l
    gemm_pv<<<dim3(8, 16, 4), dim3(256), 0, stream>>>(P, Vt, out, lsum);
}

// Round 3
// 245.795 us; speedup vs baseline: 1.0349x; 1.0065x over previous
//
#include <hip/hip_runtime.h>
#include <cstdint>
#include <cstddef>

typedef __bf16 bf16;
typedef __bf16 bf16x4 __attribute__((ext_vector_type(4)));
typedef __bf16 bf16x8 __attribute__((ext_vector_type(8)));
typedef float  f32x4  __attribute__((ext_vector_type(4)));
typedef float  f32x16 __attribute__((ext_vector_type(16)));

#define BATCH 4
#define SEQ   2048
#define DIM   1024
#define LDP   2112   // padded leading dim for P and Vt

// RNE float -> bf16
__device__ __forceinline__ bf16 to_bf16(float f) {
    unsigned u = __builtin_bit_cast(unsigned, f);
    u += 0x7fffu + ((u >> 16) & 1u);
    unsigned short h = (unsigned short)(u >> 16);
    return __builtin_bit_cast(bf16, h);
}

// async global->LDS, 16B per lane. LDS base must be wave-uniform; HW adds lane*16.
__device__ __forceinline__ void load16_lds(const bf16* g, bf16* l) {
    __builtin_amdgcn_global_load_lds(
        (__attribute__((address_space(1))) void*)(g),
        (__attribute__((address_space(3))) void*)(l),
        16, 0, 0);
}

#define BARRIER() do { asm volatile("" ::: "memory"); \
                       __builtin_amdgcn_s_barrier();  \
                       asm volatile("" ::: "memory"); } while (0)
// Plain asm lgkmcnt(0): ds_reads here are compiler-visible, so the compiler's
// own fine-grained waitcnts guarantee correctness; NO sched_barrier(0) (m141:
// order-pinning cost -42% -- that was round 2's regression).
#define LGKM0()   asm volatile("s_waitcnt lgkmcnt(0)" ::: "memory")
#define VM4()     asm volatile("s_waitcnt vmcnt(4)" ::: "memory")
#define VM0()     asm volatile("s_waitcnt vmcnt(0)" ::: "memory")

// ---------------------------------------------------------------------------
// 8-phase 256x256 core (BK=64), 512 threads = 8 waves (2M x 4N), per-wave
// 128x64 output, 16x16x32 MFMA. LDS: As/Bs each [2 dbuf][256 rows][64 k] bf16
// = 64 KB each, 128 KB total -> 1 block/CU, 2 waves/SIMD.
// Chunk swizzle: physical 16B-chunk p = logical c ^ (row&7); staged via
// pre-swizzled GLOBAL source (linear LDS dest for global_load_lds).
// Schedule (race-free by construction): during tile t,
//   P0: read a[m0-3],b[n0-1]; stage B1(t+1) -> other buffer (safe)
//   P1: read b[n2-3];          stage A1(t+1) -> other buffer (safe)
//   P2: read a[m4-7];          stage B0(t+2) -> CURRENT buf, B rows 0-127;
//       those rows' reads (waves wc=0,1) drained at P1's lgkmcnt + barrier
//   P3: (no reads);            stage A0(t+2) -> CURRENT buf, A rows 0-127;
//       those rows' reads (waves wr=0) drained at P2's lgkmcnt + barrier
// Boundary: vmcnt(4) once per tile (4 half-tiles outstanding, retire 2),
// never vmcnt(0) except at the t+2>=NT tail.
// ---------------------------------------------------------------------------

// stage one half-tile: 128 rows x 64 k of one matrix (2 gload_lds / thread).
__device__ __forceinline__ void stage_half(
    const bf16* __restrict__ srcRow0, int ld, int k0, bf16* dstHalfBase)
{
    const int tid  = threadIdx.x;
    const int wave = tid >> 6;
    const int lane = tid & 63;
    const int rg   = lane >> 3;                 // row within 8-row group
    const int scoff = ((lane & 7) ^ rg) * 8;    // pre-swizzled global chunk
#pragma unroll
    for (int j = 0; j < 2; ++j) {
        const int r = wave * 16 + j * 8;        // wave-uniform LDS row base
        load16_lds(srcRow0 + (size_t)(r + rg) * ld + k0 + scoff,
                   dstHalfBase + r * 64);
    }
}

template<int MB, int NB>
__device__ __forceinline__ void mfma_quad(
    const bf16x8 a[4][2], const bf16x8 b[4][2], f32x4 acc[8][4])
{
    __builtin_amdgcn_s_setprio(1);
#pragma unroll
    for (int m = 0; m < 4; ++m)
#pragma unroll
        for (int n = 0; n < 2; ++n)
#pragma unroll
            for (int ks = 0; ks < 2; ++ks)
                acc[MB + m][NB + n] = __builtin_amdgcn_mfma_f32_16x16x32_bf16(
                    a[m][ks], b[NB + n][ks], acc[MB + m][NB + n], 0, 0, 0);
    __builtin_amdgcn_s_setprio(0);
}

__device__ __forceinline__ void gemm8_core(
    const bf16* __restrict__ Ablk, const bf16* __restrict__ Bblk,
    int K, int lda, int ldb, bf16* As, bf16* Bs, f32x4 acc[8][4])
{
    const int tid  = threadIdx.x;
    const int lane = tid & 63;
    const int wave = tid >> 6;
    const int wr   = wave >> 2;          // 0..1 (M)
    const int wc   = wave & 3;           // 0..3 (N)
    const int r16  = lane & 15;
    const int g    = lane >> 4;
    const int r7   = r16 & 7;
    const int pk0  = ((g) ^ r7) * 8;         // phys chunk offset, ks=0
    const int pk1  = ((4 + g) ^ r7) * 8;     // ks=1
    const int arow = (wr * 128 + r16) * 64;
    const int brow = (wc * 64 + r16) * 64;
    const int NT   = K >> 6;

    // prologue: tile0 {B0,A0,B1,A1} + tile1 {B0,A0}  (order matters for vmcnt)
    stage_half(Bblk, ldb, 0, Bs);
    stage_half(Ablk, lda, 0, As);
    stage_half(Bblk + (size_t)128 * ldb, ldb, 0, Bs + 8192);
    stage_half(Ablk + (size_t)128 * lda, lda, 0, As + 8192);
    stage_half(Bblk, ldb, 64, Bs + 16384);
    stage_half(Ablk, lda, 64, As + 16384);
    VM4();                                // tile0 resident; tile1 B0/A0 in flight
    BARRIER();

    bf16x8 a[4][2], b[4][2];
#pragma unroll 2
    for (int t = 0; t < NT; ++t) {
        bf16* Ac = As + (t & 1) * 16384;
        bf16* Bc = Bs + (t & 1) * 16384;
        bf16* An = As + ((t + 1) & 1) * 16384;
        bf16* Bn = Bs + ((t + 1) & 1) * 16384;
        const int k1 = (t + 1) << 6;
        const int k2 = (t + 2) << 6;

        // ---- P0: a[m0-3], b[n0-1]; stage B1(t+1)
#pragma unroll
        for (int m = 0; m < 4; ++m) {
            a[m][0] = *(const bf16x8*)(Ac + arow + m * 1024 + pk0);
            a[m][1] = *(const bf16x8*)(Ac + arow + m * 1024 + pk1);
        }
#pragma unroll
        for (int n = 0; n < 2; ++n) {
            b[n][0] = *(const bf16x8*)(Bc + brow + n * 1024 + pk0);
            b[n][1] = *(const bf16x8*)(Bc + brow + n * 1024 + pk1);
        }
        if (t + 1 < NT) stage_half(Bblk + (size_t)128 * ldb, ldb, k1, Bn + 8192);
        BARRIER(); LGKM0();
        mfma_quad<0, 0>(a, b, acc);
        BARRIER();

        // ---- P1: b[n2-3]; stage A1(t+1)
#pragma unroll
        for (int n = 2; n < 4; ++n) {
            b[n][0] = *(const bf16x8*)(Bc + brow + n * 1024 + pk0);
            b[n][1] = *(const bf16x8*)(Bc + brow + n * 1024 + pk1);
        }
        if (t + 1 < NT) stage_half(Ablk + (size_t)128 * lda, lda, k1, An + 8192);
        BARRIER(); LGKM0();
        mfma_quad<0, 2>(a, b, acc);
        BARRIER();

        // ---- P2: a[m4-7]; stage B0(t+2) into current buffer (B free since P1)
#pragma unroll
        for (int m = 0; m < 4; ++m) {
            a[m][0] = *(const bf16x8*)(Ac + arow + 4096 + m * 1024 + pk0);
            a[m][1] = *(const bf16x8*)(Ac + arow + 4096 + m * 1024 + pk1);
        }
        if (t + 2 < NT) stage_half(Bblk, ldb, k2, Bc);
        BARRIER(); LGKM0();
        mfma_quad<4, 2>(a, b, acc);
        BARRIER();

        // ---- P3: stage A0(t+2) into current buffer (A free since P2)
        if (t + 2 < NT) stage_half(Ablk, lda, k2, Ac);
        BARRIER(); LGKM0();
        mfma_quad<4, 0>(a, b, acc);
        if (t + 1 < NT) {
            if (t + 2 < NT) { VM4(); } else { VM0(); }
        }
        BARRIER();
    }
}

// ---------------------------------------------------------------------------
// Legacy 32x32x16 128-tile core (still used by gemm_pv this round)
// ---------------------------------------------------------------------------
__device__ __forceinline__ void stage_tiles(
    const bf16* __restrict__ Abase, const bf16* __restrict__ Bbase,
    int k0, int lda, int ldb, bf16* As, bf16* Bs)
{
    const int tid   = threadIdx.x;
    const int wave  = tid >> 6;
    const int lane  = tid & 63;
    const int srow0 = wave * 8 + (lane >> 3);
    const int scoff = (((lane & 7) ^ ((lane >> 3) & 7)) * 8);
    const int ldsW  = wave * 512;
#pragma unroll
    for (int j = 0; j < 4; ++j) {
        load16_lds(Abase + (size_t)(j * 32 + srow0) * lda + k0 + scoff,
                   As + j * 2048 + ldsW);
        load16_lds(Bbase + (size_t)(j * 32 + srow0) * ldb + k0 + scoff,
                   Bs + j * 2048 + ldsW);
    }
}

__device__ __forceinline__ void gemm_core64_32(
    const bf16* __restrict__ Abase, const bf16* __restrict__ Bbase,
    int K, int lda, int ldb, bf16* As, bf16* Bs, f32x16 acc[2][2])
{
    const int tid  = threadIdx.x;
    const int lane = tid & 63;
    const int wave = tid >> 6;
    const int wm   = (wave >> 1) * 64;
    const int wn   = (wave & 1) * 64;
    const int r32  = lane & 31;
    const int hi   = lane >> 5;

    for (int k0 = 0; k0 < K; k0 += 64) {
        __syncthreads();
        stage_tiles(Abase, Bbase, k0, lda, ldb, As, Bs);
        __syncthreads();
#pragma unroll
        for (int t = 0; t < 4; ++t) {
            bf16x8 af[2], bfr[2];
            const int p = (2 * t + hi) ^ (r32 & 7);
#pragma unroll
            for (int i = 0; i < 2; ++i) {
                af[i]  = *(const bf16x8*)(As + (wm + i * 32 + r32) * 64 + p * 8);
                bfr[i] = *(const bf16x8*)(Bs + (wn + i * 32 + r32) * 64 + p * 8);
            }
#pragma unroll
            for (int mi = 0; mi < 2; ++mi)
#pragma unroll
                for (int ni = 0; ni < 2; ++ni)
                    acc[mi][ni] = __builtin_amdgcn_mfma_f32_32x32x16_bf16(
                        af[mi], bfr[ni], acc[mi][ni], 0, 0, 0);
        }
    }
}

__device__ __forceinline__ int c32_row(int reg, int hi) {
    return (reg & 3) + 8 * (reg >> 2) + 4 * hi;
}

// ---------------------------------------------------------------------------
// Merged projection (8-phase 256^2): blocks [0,256) -> Q,K = X @ W{q,k}T^T;
// blocks [256,384) -> Vt[b] = WvT @ X[b]^T.
// ---------------------------------------------------------------------------
__global__ __launch_bounds__(512, 2) void proj_gemm8(
    const bf16* __restrict__ xb, const bf16* __restrict__ Wt,
    bf16* __restrict__ Q, bf16* __restrict__ Kb, bf16* __restrict__ Vt)
{
    __shared__ bf16 As[32768];
    __shared__ bf16 Bs[32768];
    f32x4 acc[8][4] = {};

    const int r = blockIdx.x;
    const bf16 *Ab, *Bb;
    bf16* Cb;
    int ldc;
    if (r < 256) {                        // Q/K part
        const int my = r >> 3, j = r & 7;
        Ab = xb + (size_t)my * 256 * DIM;
        Bb = Wt + (size_t)((j >> 2) ? DIM * DIM : 0) + (size_t)(j & 3) * 256 * DIM;
        bf16* dst = (j >> 2) ? Kb : Q;
        Cb = dst + (size_t)my * 256 * DIM + (size_t)(j & 3) * 256;
        ldc = DIM;
    } else {                              // Vt part
        const int u = r - 256;
        const int bz = u >> 5, w = u & 31;
        const int vy = w >> 3, vx = w & 7;
        Ab = Wt + (size_t)2 * DIM * DIM + (size_t)vy * 256 * DIM;
        Bb = xb + (size_t)bz * SEQ * DIM + (size_t)vx * 256 * DIM;
        Cb = Vt + (size_t)bz * DIM * LDP + (size_t)vy * 256 * LDP + (size_t)vx * 256;
        ldc = LDP;
    }
    gemm8_core(Ab, Bb, DIM, DIM, DIM, As, Bs, acc);

    const int lane = threadIdx.x & 63;
    const int wave = threadIdx.x >> 6;
    const int wr = wave >> 2, wc = wave & 3;
    const int r16 = lane & 15, g = lane >> 4;
    const int row0 = wr * 128 + g * 4;
    const int col0 = wc * 64 + r16;
#pragma unroll
    for (int m = 0; m < 8; ++m)
#pragma unroll
        for (int n = 0; n < 4; ++n)
#pragma unroll
            for (int rr = 0; rr < 4; ++rr)
                Cb[(size_t)(row0 + m * 16 + rr) * ldc + col0 + n * 16] =
                    to_bf16(acc[m][n][rr]);
}

// ---------------------------------------------------------------------------
// scores (8-phase 256^2): P' = exp((Q @ K^T)/32) (bf16, ldc=LDP), fp32 row
// sums via atomics. grid = 256 blocks (bz*64 + by*8 + bx) -> exactly 1/CU.
// ---------------------------------------------------------------------------
__global__ __launch_bounds__(512, 2) void gemm_scores8(
    const bf16* __restrict__ Qm, const bf16* __restrict__ Kb,
    bf16* __restrict__ P, float* __restrict__ lsum)
{
    __shared__ bf16 As[32768];
    __shared__ bf16 Bs[32768];
    f32x4 acc[8][4] = {};

    const int d = blockIdx.x;
    const int bx = d & 7, by = (d >> 3) & 7, bz = d >> 6;
    const bf16* Ab = Qm + (size_t)bz * SEQ * DIM + (size_t)by * 256 * DIM;
    const bf16* Bb = Kb + (size_t)bz * SEQ * DIM + (size_t)bx * 256 * DIM;
    gemm8_core(Ab, Bb, DIM, DIM, DIM, As, Bs, acc);

    bf16* Cb  = P + (size_t)bz * SEQ * LDP;
    float* ls = lsum + (size_t)bz * SEQ;
    const int lane = threadIdx.x & 63;
    const int wave = threadIdx.x >> 6;
    const int wr = wave >> 2, wc = wave & 3;
    const int r16 = lane & 15, g = lane >> 4;
    const int rowB = by * 256 + wr * 128 + g * 4;
    const int colB = bx * 256 + wc * 64 + r16;
#pragma unroll
    for (int m = 0; m < 8; ++m)
#pragma unroll
        for (int rr = 0; rr < 4; ++rr) {
            float s = 0.0f;
#pragma unroll
            for (int n = 0; n < 4; ++n) {
                const float e = __expf(acc[m][n][rr] * 0.03125f);
                s += e;
                Cb[(size_t)(rowB + m * 16 + rr) * LDP + colB + n * 16] = to_bf16(e);
            }
            s += __shfl_xor(s, 1);
            s += __shfl_xor(s, 2);
            s += __shfl_xor(s, 4);
            s += __shfl_xor(s, 8);
            if (r16 == 0)
                atomicAdd(ls + rowB + m * 16 + rr, s);
        }
}

// ---------------------------------------------------------------------------
// PV GEMM (legacy 32x32 core): out = (P' @ Vt^T) / l, fp32. grid = (8, 16, 4).
// ---------------------------------------------------------------------------
__global__ __launch_bounds__(256, 4) void gemm_pv(
    const bf16* __restrict__ P, const bf16* __restrict__ Vt, float* __restrict__ C,
    const float* __restrict__ lsum)
{
    __shared__ bf16 As[8192];
    __shared__ bf16 Bs[8192];
    f32x16 acc[2][2] = {};

    const int d = blockIdx.x + 8 * (blockIdx.y + 16 * blockIdx.z);
    const int c = d & 7, j = d >> 3;
    const int bx = j & 7;
    const int p = c + 8 * (j >> 3);
    const int by = p & 15, bz = p >> 4;

    const bf16* Ab = P  + (size_t)bz * SEQ * LDP + (size_t)by * 128 * LDP;
    const bf16* Bb = Vt + (size_t)bz * DIM * LDP + (size_t)bx * 128 * LDP;
    float* Cb = C + (size_t)bz * SEQ * DIM;
    gemm_core64_32(Ab, Bb, SEQ, LDP, LDP, As, Bs, acc);

    const int lane = threadIdx.x & 63;
    const int wave = threadIdx.x >> 6;
    const int hi = lane >> 5, r32 = lane & 31;
    const int wm = (wave >> 1) * 64, wn = (wave & 1) * 64;
    const int rowBase = by * 128 + wm;
    const int colBase = bx * 128 + wn + r32;
    const float* ls = lsum + (size_t)bz * SEQ;
#pragma unroll
    for (int mi = 0; mi < 2; ++mi)
#pragma unroll
        for (int reg = 0; reg < 16; ++reg) {
            const int row = rowBase + mi * 32 + c32_row(reg, hi);
            const float inv = __builtin_amdgcn_rcpf(ls[row]);
#pragma unroll
            for (int ni = 0; ni < 2; ++ni)
                Cb[(size_t)row * DIM + colBase + ni * 32] = acc[mi][ni][reg] * inv;
        }
}

// ---------------------------------------------------------------------------
// Fused prep: blocks [0,8192) cast x fp32->bf16; blocks [8192,11264) transpose
// + cast weights; block 11264 zeroes lsum. All branches block-uniform.
// ---------------------------------------------------------------------------
__global__ __launch_bounds__(256) void prep(
    const float* __restrict__ x,  const float* __restrict__ wq,
    const float* __restrict__ wk, const float* __restrict__ wv,
    bf16* __restrict__ xb, bf16* __restrict__ Wt, float* __restrict__ lsum)
{
    __shared__ float tile[32][33];
    const int b = blockIdx.x;
    const int tid = threadIdx.x;
    if (b < 8192) {
        const size_t i = ((size_t)b * 256 + tid) * 4;
        const float4 v = *(const float4*)(x + i);
        bf16x4 o = { to_bf16(v.x), to_bf16(v.y), to_bf16(v.z), to_bf16(v.w) };
        *(bf16x4*)(xb + i) = o;
    } else if (b < 8192 + 3072) {
        const int t   = b - 8192;
        const int sel = t >> 10;
        const int n0  = (t & 31) * 32;
        const int k0  = ((t >> 5) & 31) * 32;
        const float* w = (sel == 0) ? wq : (sel == 1) ? wk : wv;
        const int tx = tid & 31, ty = tid >> 5;
#pragma unroll
        for (int j = 0; j < 32; j += 8)
            tile[ty + j][tx] = w[(size_t)(k0 + ty + j) * 1024 + n0 + tx];
        __syncthreads();
        bf16* dst = Wt + (size_t)sel * 1024 * 1024;
#pragma unroll
        for (int j = 0; j < 32; j += 8)
            dst[(size_t)(n0 + ty + j) * 1024 + k0 + tx] = to_bf16(tile[tx][ty + j]);
    } else {
#pragma unroll
        for (int i = 0; i < 32; ++i)
            lsum[i * 256 + tid] = 0.0f;
    }
}

// ---------------------------------------------------------------------------
extern "C" void kernel_launch(void* const* d_in, const int* in_sizes, int n_in,
                              void* d_out, int out_size, void* d_ws, size_t ws_size,
                              hipStream_t stream)
{
    const float* x  = (const float*)d_in[0];
    const float* wq = (const float*)d_in[1];
    const float* wk = (const float*)d_in[2];
    const float* wv = (const float*)d_in[3];
    float* out = (float*)d_out;
    char* ws = (char*)d_ws;

    // workspace layout (bytes)
    bf16*  xb   = (bf16*)(ws);                   // 16 MB [8192,1024]
    bf16*  Wt   = (bf16*)(ws + (16u << 20));     //  6 MB [3072,1024] (WqT|WkT|WvT)
    bf16*  Q    = (bf16*)(ws + (22u << 20));     // 16 MB [8192,1024]
    bf16*  Kb   = (bf16*)(ws + (38u << 20));     // 16 MB [8192,1024]
    bf16*  Vt   = (bf16*)(ws + (54u << 20));     // 17 MB [4][1024][LDP]
    bf16*  P    = (bf16*)(ws + (72u << 20));     // 33 MB [4][2048][LDP]
    float* lsum = (float*)(ws + (108u << 20));   // 32 KB [8192]

    prep<<<dim3(8192 + 3072 + 1), dim3(256), 0, stream>>>(
        x, wq, wk, wv, xb, Wt, lsum);

    // Q, K, Vt in one dispatch (8-phase 256^2 core)
    proj_gemm8<<<dim3(384), dim3(512), 0, stream>>>(xb, Wt, Q, Kb, Vt);

    // P' = exp(Q @ K^T / 32), row sums -> lsum (8-phase 256^2 core)
    gemm_scores8<<<dim3(256), dim3(512), 0, stream>>>(Q, Kb, P, lsum);

    // out = (P' @ Vt^T) / l
    gemm_pv<<<dim3(8, 16, 4), dim3(256), 0, stream>>>(P, Vt, out, lsum);
}

// Round 4
// 233.685 us; speedup vs baseline: 1.0886x; 1.0518x over previous
//
#include <hip/hip_runtime.h>
#include <cstdint>
#include <cstddef>

typedef __bf16 bf16;
typedef __bf16 bf16x4 __attribute__((ext_vector_type(4)));
typedef __bf16 bf16x8 __attribute__((ext_vector_type(8)));
typedef float  f32x4  __attribute__((ext_vector_type(4)));
typedef float  f32x16 __attribute__((ext_vector_type(16)));

#define BATCH 4
#define SEQ   2048
#define DIM   1024
#define LDP   2112   // padded leading dim for P and Vt

// RNE float -> bf16
__device__ __forceinline__ bf16 to_bf16(float f) {
    unsigned u = __builtin_bit_cast(unsigned, f);
    u += 0x7fffu + ((u >> 16) & 1u);
    unsigned short h = (unsigned short)(u >> 16);
    return __builtin_bit_cast(bf16, h);
}

// async global->LDS, 16B per lane. LDS base must be wave-uniform; HW adds lane*16.
__device__ __forceinline__ void load16_lds(const bf16* g, bf16* l) {
    __builtin_amdgcn_global_load_lds(
        (__attribute__((address_space(1))) void*)(g),
        (__attribute__((address_space(3))) void*)(l),
        16, 0, 0);
}

#define BARRIER() do { asm volatile("" ::: "memory"); \
                       __builtin_amdgcn_s_barrier();  \
                       asm volatile("" ::: "memory"); } while (0)
#define LGKM0()   asm volatile("s_waitcnt lgkmcnt(0)" ::: "memory")
#define VM0()     asm volatile("s_waitcnt vmcnt(0)" ::: "memory")

// ---------------------------------------------------------------------------
// Big-phase 256x256 core (BK=64), 512 threads = 8 waves (2M x 4N), per-wave
// 128x64 output, 16x16x32 MFMA. LDS 128 KB (2 dbuf x (A 256x64 + B 256x64)).
// ONE barrier per K-tile; no intra-tile lgkmcnt(0)/barrier fences:
//   - issue all B-frag + A-half0 ds_reads
//   - issue the FULL t+1 stage (8 global_load_lds) into the OTHER buffer
//     (never conflicts with current-tile reads -> no mid-tile barrier needed)
//   - MFMA half0; A-half1 ds_reads (compiler hoists into MFMA stream with
//     counted lgkmcnt -- m97-verified codegen); MFMA half1
//   - lgkmcnt(0) (safety: all cur-buf reads retired before anyone overwrites
//     next tile), vmcnt(0) (t+1 loads issued a FULL tile ago -> latency
//     covered), barrier.
// Rationale: per-CU per-tile LDS port time (192 ds_read_b128 ~ 2300 cyc) is
// co-equal with MFMA time (~2060 cyc); barrier-locked read/MFMA windows
// serialize them (rounds 2-3: MfmaUtil 25%). This structure overlaps them.
// Chunk swizzle: LDS[row][p] = global[row][p ^ (row&7)] via pre-swizzled
// global source; readers use pk = (c ^ (row&7))*8. Bank conflicts = 0 (r2).
// ---------------------------------------------------------------------------

// stage one half-tile: 128 rows x 64 k of one matrix (2 gload_lds / thread).
__device__ __forceinline__ void stage_half(
    const bf16* __restrict__ srcRow0, int ld, int k0, bf16* dstHalfBase)
{
    const int tid  = threadIdx.x;
    const int wave = tid >> 6;
    const int lane = tid & 63;
    const int rg   = lane >> 3;                 // row within 8-row group
    const int scoff = ((lane & 7) ^ rg) * 8;    // pre-swizzled global chunk
#pragma unroll
    for (int j = 0; j < 2; ++j) {
        const int r = wave * 16 + j * 8;        // wave-uniform LDS row base
        load16_lds(srcRow0 + (size_t)(r + rg) * ld + k0 + scoff,
                   dstHalfBase + r * 64);
    }
}

__device__ __forceinline__ void gemm_big_core(
    const bf16* __restrict__ Ablk, const bf16* __restrict__ Bblk,
    int K, int lda, int ldb, bf16* As, bf16* Bs, f32x4 acc[8][4])
{
    const int tid  = threadIdx.x;
    const int lane = tid & 63;
    const int wave = tid >> 6;
    const int wr   = wave >> 2;          // 0..1 (M)
    const int wc   = wave & 3;           // 0..3 (N)
    const int r16  = lane & 15;
    const int g    = lane >> 4;
    const int r7   = r16 & 7;
    const int pk0  = ((g) ^ r7) * 8;         // phys chunk offset, ks=0
    const int pk1  = ((4 + g) ^ r7) * 8;     // ks=1
    const int arow = (wr * 128 + r16) * 64;
    const int brow = (wc * 64 + r16) * 64;
    const int NT   = K >> 6;

    // prologue: stage tile 0 into buffer 0
    stage_half(Bblk, ldb, 0, Bs);
    stage_half(Bblk + (size_t)128 * ldb, ldb, 0, Bs + 8192);
    stage_half(Ablk, lda, 0, As);
    stage_half(Ablk + (size_t)128 * lda, lda, 0, As + 8192);
    VM0();
    BARRIER();

#pragma unroll 2
    for (int t = 0; t < NT; ++t) {
        bf16* Ac = As + (t & 1) * 16384;
        bf16* Bc = Bs + (t & 1) * 16384;
        bf16* An = As + ((t + 1) & 1) * 16384;
        bf16* Bn = Bs + ((t + 1) & 1) * 16384;
        const int k1 = (t + 1) << 6;

        bf16x8 b[4][2], a[4][2], a2[4][2];
        // all B frags + A half0 frags
#pragma unroll
        for (int n = 0; n < 4; ++n) {
            b[n][0] = *(const bf16x8*)(Bc + brow + n * 1024 + pk0);
            b[n][1] = *(const bf16x8*)(Bc + brow + n * 1024 + pk1);
        }
#pragma unroll
        for (int m = 0; m < 4; ++m) {
            a[m][0] = *(const bf16x8*)(Ac + arow + m * 1024 + pk0);
            a[m][1] = *(const bf16x8*)(Ac + arow + m * 1024 + pk1);
        }
        // full t+1 stage -> other buffer (in flight for an entire tile)
        if (t + 1 < NT) {
            stage_half(Bblk, ldb, k1, Bn);
            stage_half(Bblk + (size_t)128 * ldb, ldb, k1, Bn + 8192);
            stage_half(Ablk, lda, k1, An);
            stage_half(Ablk + (size_t)128 * lda, lda, k1, An + 8192);
        }
        // MFMA half0 (m0-3 x n0-3 x ks0-1): compiler emits counted lgkmcnt
#pragma unroll
        for (int m = 0; m < 4; ++m)
#pragma unroll
            for (int n = 0; n < 4; ++n)
#pragma unroll
                for (int ks = 0; ks < 2; ++ks)
                    acc[m][n] = __builtin_amdgcn_mfma_f32_16x16x32_bf16(
                        a[m][ks], b[n][ks], acc[m][n], 0, 0, 0);
        // A half1 frags (compiler may hoist into the MFMA stream above)
#pragma unroll
        for (int m = 0; m < 4; ++m) {
            a2[m][0] = *(const bf16x8*)(Ac + arow + 4096 + m * 1024 + pk0);
            a2[m][1] = *(const bf16x8*)(Ac + arow + 4096 + m * 1024 + pk1);
        }
        // MFMA half1 (m4-7)
#pragma unroll
        for (int m = 0; m < 4; ++m)
#pragma unroll
            for (int n = 0; n < 4; ++n)
#pragma unroll
                for (int ks = 0; ks < 2; ++ks)
                    acc[4 + m][n] = __builtin_amdgcn_mfma_f32_16x16x32_bf16(
                        a2[m][ks], b[n][ks], acc[4 + m][n], 0, 0, 0);

        LGKM0();                      // all cur-buf reads retired (cheap: done)
        if (t + 1 < NT) VM0();        // t+1 resident; issued a full tile ago
        BARRIER();
    }
}

// shared bf16 C-writer for the 256^2 core
__device__ __forceinline__ void write_c256(
    bf16* __restrict__ Cb, int ldc, const f32x4 acc[8][4])
{
    const int lane = threadIdx.x & 63;
    const int wave = threadIdx.x >> 6;
    const int wr = wave >> 2, wc = wave & 3;
    const int r16 = lane & 15, g = lane >> 4;
    const int row0 = wr * 128 + g * 4;
    const int col0 = wc * 64 + r16;
#pragma unroll
    for (int m = 0; m < 8; ++m)
#pragma unroll
        for (int n = 0; n < 4; ++n)
#pragma unroll
            for (int rr = 0; rr < 4; ++rr)
                Cb[(size_t)(row0 + m * 16 + rr) * ldc + col0 + n * 16] =
                    to_bf16(acc[m][n][rr]);
}

// ---------------------------------------------------------------------------
// Legacy 32x32x16 128-tile core (still used by gemm_pv this round)
// ---------------------------------------------------------------------------
__device__ __forceinline__ void stage_tiles(
    const bf16* __restrict__ Abase, const bf16* __restrict__ Bbase,
    int k0, int lda, int ldb, bf16* As, bf16* Bs)
{
    const int tid   = threadIdx.x;
    const int wave  = tid >> 6;
    const int lane  = tid & 63;
    const int srow0 = wave * 8 + (lane >> 3);
    const int scoff = (((lane & 7) ^ ((lane >> 3) & 7)) * 8);
    const int ldsW  = wave * 512;
#pragma unroll
    for (int j = 0; j < 4; ++j) {
        load16_lds(Abase + (size_t)(j * 32 + srow0) * lda + k0 + scoff,
                   As + j * 2048 + ldsW);
        load16_lds(Bbase + (size_t)(j * 32 + srow0) * ldb + k0 + scoff,
                   Bs + j * 2048 + ldsW);
    }
}

__device__ __forceinline__ void gemm_core64_32(
    const bf16* __restrict__ Abase, const bf16* __restrict__ Bbase,
    int K, int lda, int ldb, bf16* As, bf16* Bs, f32x16 acc[2][2])
{
    const int tid  = threadIdx.x;
    const int lane = tid & 63;
    const int wave = tid >> 6;
    const int wm   = (wave >> 1) * 64;
    const int wn   = (wave & 1) * 64;
    const int r32  = lane & 31;
    const int hi   = lane >> 5;

    for (int k0 = 0; k0 < K; k0 += 64) {
        __syncthreads();
        stage_tiles(Abase, Bbase, k0, lda, ldb, As, Bs);
        __syncthreads();
#pragma unroll
        for (int t = 0; t < 4; ++t) {
            bf16x8 af[2], bfr[2];
            const int p = (2 * t + hi) ^ (r32 & 7);
#pragma unroll
            for (int i = 0; i < 2; ++i) {
                af[i]  = *(const bf16x8*)(As + (wm + i * 32 + r32) * 64 + p * 8);
                bfr[i] = *(const bf16x8*)(Bs + (wn + i * 32 + r32) * 64 + p * 8);
            }
#pragma unroll
            for (int mi = 0; mi < 2; ++mi)
#pragma unroll
                for (int ni = 0; ni < 2; ++ni)
                    acc[mi][ni] = __builtin_amdgcn_mfma_f32_32x32x16_bf16(
                        af[mi], bfr[ni], acc[mi][ni], 0, 0, 0);
        }
    }
}

__device__ __forceinline__ int c32_row(int reg, int hi) {
    return (reg & 3) + 8 * (reg >> 2) + 4 * hi;
}

// ---------------------------------------------------------------------------
// proj_qk (big-phase 256^2): 256 blocks -> Q,K = X @ W{q,k}T^T. Exactly 1/CU.
// ---------------------------------------------------------------------------
__global__ __launch_bounds__(512, 2) void proj_qk(
    const bf16* __restrict__ xb, const bf16* __restrict__ Wt,
    bf16* __restrict__ Q, bf16* __restrict__ Kb)
{
    __shared__ bf16 As[32768];
    __shared__ bf16 Bs[32768];
    f32x4 acc[8][4] = {};

    const int r = blockIdx.x;
    const int my = r >> 3, j = r & 7;
    const bf16* Ab = xb + (size_t)my * 256 * DIM;
    const bf16* Bb = Wt + (size_t)((j >> 2) ? DIM * DIM : 0)
                        + (size_t)(j & 3) * 256 * DIM;
    bf16* dst = (j >> 2) ? Kb : Q;
    bf16* Cb = dst + (size_t)my * 256 * DIM + (size_t)(j & 3) * 256;

    gemm_big_core(Ab, Bb, DIM, DIM, DIM, As, Bs, acc);
    write_c256(Cb, DIM, acc);
}

// ---------------------------------------------------------------------------
// proj_v (big-phase 256^2): 128 blocks -> Vt[b] = WvT @ X[b]^T.
// ---------------------------------------------------------------------------
__global__ __launch_bounds__(512, 2) void proj_v(
    const bf16* __restrict__ xb, const bf16* __restrict__ Wt,
    bf16* __restrict__ Vt)
{
    __shared__ bf16 As[32768];
    __shared__ bf16 Bs[32768];
    f32x4 acc[8][4] = {};

    const int u = blockIdx.x;
    const int bz = u >> 5, w = u & 31;
    const int vy = w >> 3, vx = w & 7;
    const bf16* Ab = Wt + (size_t)2 * DIM * DIM + (size_t)vy * 256 * DIM;
    const bf16* Bb = xb + (size_t)bz * SEQ * DIM + (size_t)vx * 256 * DIM;
    bf16* Cb = Vt + (size_t)bz * DIM * LDP + (size_t)vy * 256 * LDP
                  + (size_t)vx * 256;

    gemm_big_core(Ab, Bb, DIM, DIM, DIM, As, Bs, acc);
    write_c256(Cb, LDP, acc);
}

// ---------------------------------------------------------------------------
// scores (big-phase 256^2): P' = exp((Q @ K^T)/32) (bf16, ldc=LDP), fp32 row
// sums via atomics. grid = 256 blocks (bz*64 + by*8 + bx) -> exactly 1/CU.
// ---------------------------------------------------------------------------
__global__ __launch_bounds__(512, 2) void gemm_scores8(
    const bf16* __restrict__ Qm, const bf16* __restrict__ Kb,
    bf16* __restrict__ P, float* __restrict__ lsum)
{
    __shared__ bf16 As[32768];
    __shared__ bf16 Bs[32768];
    f32x4 acc[8][4] = {};

    const int d = blockIdx.x;
    const int bx = d & 7, by = (d >> 3) & 7, bz = d >> 6;
    const bf16* Ab = Qm + (size_t)bz * SEQ * DIM + (size_t)by * 256 * DIM;
    const bf16* Bb = Kb + (size_t)bz * SEQ * DIM + (size_t)bx * 256 * DIM;
    gemm_big_core(Ab, Bb, DIM, DIM, DIM, As, Bs, acc);

    bf16* Cb  = P + (size_t)bz * SEQ * LDP;
    float* ls = lsum + (size_t)bz * SEQ;
    const int lane = threadIdx.x & 63;
    const int wave = threadIdx.x >> 6;
    const int wr = wave >> 2, wc = wave & 3;
    const int r16 = lane & 15, g = lane >> 4;
    const int rowB = by * 256 + wr * 128 + g * 4;
    const int colB = bx * 256 + wc * 64 + r16;
#pragma unroll
    for (int m = 0; m < 8; ++m)
#pragma unroll
        for (int rr = 0; rr < 4; ++rr) {
            float s = 0.0f;
#pragma unroll
            for (int n = 0; n < 4; ++n) {
                const float e = __expf(acc[m][n][rr] * 0.03125f);
                s += e;
                Cb[(size_t)(rowB + m * 16 + rr) * LDP + colB + n * 16] = to_bf16(e);
            }
            s += __shfl_xor(s, 1);
            s += __shfl_xor(s, 2);
            s += __shfl_xor(s, 4);
            s += __shfl_xor(s, 8);
            if (r16 == 0)
                atomicAdd(ls + rowB + m * 16 + rr, s);
        }
}

// ---------------------------------------------------------------------------
// PV GEMM (legacy 32x32 core): out = (P' @ Vt^T) / l, fp32. grid = (8, 16, 4).
// ---------------------------------------------------------------------------
__global__ __launch_bounds__(256, 4) void gemm_pv(
    const bf16* __restrict__ P, const bf16* __restrict__ Vt, float* __restrict__ C,
    const float* __restrict__ lsum)
{
    __shared__ bf16 As[8192];
    __shared__ bf16 Bs[8192];
    f32x16 acc[2][2] = {};

    const int d = blockIdx.x + 8 * (blockIdx.y + 16 * blockIdx.z);
    const int c = d & 7, j = d >> 3;
    const int bx = j & 7;
    const int p = c + 8 * (j >> 3);
    const int by = p & 15, bz = p >> 4;

    const bf16* Ab = P  + (size_t)bz * SEQ * LDP + (size_t)by * 128 * LDP;
    const bf16* Bb = Vt + (size_t)bz * DIM * LDP + (size_t)bx * 128 * LDP;
    float* Cb = C + (size_t)bz * SEQ * DIM;
    gemm_core64_32(Ab, Bb, SEQ, LDP, LDP, As, Bs, acc);

    const int lane = threadIdx.x & 63;
    const int wave = threadIdx.x >> 6;
    const int hi = lane >> 5, r32 = lane & 31;
    const int wm = (wave >> 1) * 64, wn = (wave & 1) * 64;
    const int rowBase = by * 128 + wm;
    const int colBase = bx * 128 + wn + r32;
    const float* ls = lsum + (size_t)bz * SEQ;
#pragma unroll
    for (int mi = 0; mi < 2; ++mi)
#pragma unroll
        for (int reg = 0; reg < 16; ++reg) {
            const int row = rowBase + mi * 32 + c32_row(reg, hi);
            const float inv = __builtin_amdgcn_rcpf(ls[row]);
#pragma unroll
            for (int ni = 0; ni < 2; ++ni)
                Cb[(size_t)row * DIM + colBase + ni * 32] = acc[mi][ni][reg] * inv;
        }
}

// ---------------------------------------------------------------------------
// Fused prep: blocks [0,8192) cast x fp32->bf16; blocks [8192,11264) transpose
// + cast weights; block 11264 zeroes lsum. All branches block-uniform.
// ---------------------------------------------------------------------------
__global__ __launch_bounds__(256) void prep(
    const float* __restrict__ x,  const float* __restrict__ wq,
    const float* __restrict__ wk, const float* __restrict__ wv,
    bf16* __restrict__ xb, bf16* __restrict__ Wt, float* __restrict__ lsum)
{
    __shared__ float tile[32][33];
    const int b = blockIdx.x;
    const int tid = threadIdx.x;
    if (b < 8192) {
        const size_t i = ((size_t)b * 256 + tid) * 4;
        const float4 v = *(const float4*)(x + i);
        bf16x4 o = { to_bf16(v.x), to_bf16(v.y), to_bf16(v.z), to_bf16(v.w) };
        *(bf16x4*)(xb + i) = o;
    } else if (b < 8192 + 3072) {
        const int t   = b - 8192;
        const int sel = t >> 10;
        const int n0  = (t & 31) * 32;
        const int k0  = ((t >> 5) & 31) * 32;
        const float* w = (sel == 0) ? wq : (sel == 1) ? wk : wv;
        const int tx = tid & 31, ty = tid >> 5;
#pragma unroll
        for (int j = 0; j < 32; j += 8)
            tile[ty + j][tx] = w[(size_t)(k0 + ty + j) * 1024 + n0 + tx];
        __syncthreads();
        bf16* dst = Wt + (size_t)sel * 1024 * 1024;
#pragma unroll
        for (int j = 0; j < 32; j += 8)
            dst[(size_t)(n0 + ty + j) * 1024 + k0 + tx] = to_bf16(tile[tx][ty + j]);
    } else {
#pragma unroll
        for (int i = 0; i < 32; ++i)
            lsum[i * 256 + tid] = 0.0f;
    }
}

// ---------------------------------------------------------------------------
extern "C" void kernel_launch(void* const* d_in, const int* in_sizes, int n_in,
                              void* d_out, int out_size, void* d_ws, size_t ws_size,
                              hipStream_t stream)
{
    const float* x  = (const float*)d_in[0];
    const float* wq = (const float*)d_in[1];
    const float* wk = (const float*)d_in[2];
    const float* wv = (const float*)d_in[3];
    float* out = (float*)d_out;
    char* ws = (char*)d_ws;

    // workspace layout (bytes)
    bf16*  xb   = (bf16*)(ws);                   // 16 MB [8192,1024]
    bf16*  Wt   = (bf16*)(ws + (16u << 20));     //  6 MB [3072,1024] (WqT|WkT|WvT)
    bf16*  Q    = (bf16*)(ws + (22u << 20));     // 16 MB [8192,1024]
    bf16*  Kb   = (bf16*)(ws + (38u << 20));     // 16 MB [8192,1024]
    bf16*  Vt   = (bf16*)(ws + (54u << 20));     // 17 MB [4][1024][LDP]
    bf16*  P    = (bf16*)(ws + (72u << 20));     // 33 MB [4][2048][LDP]
    float* lsum = (float*)(ws + (108u << 20));   // 32 KB [8192]

    prep<<<dim3(8192 + 3072 + 1), dim3(256), 0, stream>>>(
        x, wq, wk, wv, xb, Wt, lsum);

    // Q,K (256 blocks, exact fill) then Vt (128 blocks) -- avoids the 384-block
    // 2-round quantization of the merged dispatch.
    proj_qk<<<dim3(256), dim3(512), 0, stream>>>(xb, Wt, Q, Kb);
    proj_v<<<dim3(128), dim3(512), 0, stream>>>(xb, Wt, Vt);

    // P' = exp(Q @ K^T / 32), row sums -> lsum (big-phase 256^2 core)
    gemm_scores8<<<dim3(256), dim3(512), 0, stream>>>(Q, Kb, P, lsum);

    // out = (P' @ Vt^T) / l
    gemm_pv<<<dim3(8, 16, 4), dim3(256), 0, stream>>>(P, Vt, out, lsum);
}